// Round 3
// baseline (290.159 us; speedup 1.0000x reference)
//
#include <hip/hip_runtime.h>
#include <math.h>

// BinaryTreeLSTM on MI355X — R6.
// vs R5 (261us): BN=32 — each wave computes a grp-PAIR (32 cols): per kc,
// 12 dwordx4 loads feed 20 MFMA (was 7 for 10). Halves A-redundancy
// (16x -> 8x) and cuts per-output L1 bytes ~30% (big levels are L1-BW
// bound: ~14K cy L1 vs ~6K cy MFMA per CU at B=4096).
// 1-D grid, gp = bid&7 -> grp-pair per XCD (round-robin) => per-XCD L2
// weight footprint 160KB not 1.3MB. RT=2 for leaf+B=4096 only (L1 model:
// RT1 wins wall-time when blocks < 256).
// Dispatches: prep, leaf, compose x13 = 15.

#define MEM 256

typedef __attribute__((ext_vector_type(8))) short bf16x8;
typedef __attribute__((ext_vector_type(4))) float f32x4;

__device__ __forceinline__ float sigf(float x) { return 1.0f / (1.0f + __expf(-x)); }

__device__ __forceinline__ unsigned short f2b(float f) {
  unsigned int u = __float_as_uint(f);
  u = (u + 0x7FFFu + ((u >> 16) & 1u)) >> 16;
  return (unsigned short)u;
}

// ---- Fused one-time prep: Wcf shuffle | Wxf shuffle | embs->bf16 | bias5 ----
#define NB_WCF 2560
#define NB_WXF 960
#define NB_EB 10240
__global__ __launch_bounds__(256) void k_prep(
    const float* __restrict__ Wl, const float* __restrict__ Wr,
    const float* __restrict__ Wx, const float* __restrict__ bx,
    const float* __restrict__ embs, const float* __restrict__ emb_last,
    unsigned short* __restrict__ Wcf, unsigned short* __restrict__ Wxf,
    unsigned short* __restrict__ eb, float* __restrict__ bias5) {
  int b = blockIdx.x;
  if (b < NB_WCF) {
    int idx = b * 256 + threadIdx.x;  // 1280*512
    int f = idx >> 9, r = idx & 511;
    int lane = r >> 3, j = r & 7;
    int gate = f % 5, t = f / 5;
    int grp = t & 15, kc = t >> 4;
    int k = kc * 32 + ((lane >> 4) << 3) + j;
    int n = gate * 256 + (grp << 4) + (lane & 15);
    float v = (k < 256) ? Wl[n * 256 + k] : Wr[n * 256 + (k - 256)];
    Wcf[idx] = f2b(v);
  } else if (b < NB_WCF + NB_WXF) {
    int idx = (b - NB_WCF) * 256 + threadIdx.x;  // 480*512
    int f = idx >> 9, r = idx & 511;
    int lane = r >> 3, j = r & 7;
    int gate = f % 3, t = f / 3;
    int grp = t & 15, kc = t >> 4;
    int k = kc * 32 + ((lane >> 4) << 3) + j;
    const int gmap[3] = {0, 1, 3};
    int n = gmap[gate] * 256 + (grp << 4) + (lane & 15);
    float v = (k < 300) ? Wx[n * 300 + k] : 0.0f;
    Wxf[idx] = f2b(v);
  } else if (b < NB_WCF + NB_WXF + NB_EB) {
    int idx = (b - NB_WCF - NB_WXF) * 256 + threadIdx.x;  // 8192*320
    int row = idx / 320;
    int k = idx - row * 320;
    eb[idx] = (k < 300) ? f2b(embs[row * 300 + k]) : (unsigned short)0;
  } else {
    int g = b - (NB_WCF + NB_WXF + NB_EB);  // 0..4
    __shared__ float er[300];
    for (int k = threadIdx.x; k < 300; k += 256) er[k] = emb_last[k];
    __syncthreads();
    const int map[5] = {0, 1, 2, 2, 3};
    int wrow = map[g] * 256 + threadIdx.x;
    const float* w = Wx + wrow * 300;
    float s = bx[wrow];
    for (int k = 0; k < 300; k++) s += er[k] * w[k];
    bias5[g * 256 + threadIdx.x] = s;
  }
}

// ---- Leaf: 1-D grid(512); wave = grp-pair x 2 row-tiles ----
__global__ __launch_bounds__(256) void k_leaf_mfma(
    const unsigned short* __restrict__ eb, const unsigned short* __restrict__ Wxf,
    const float* __restrict__ bx, float* __restrict__ cO,
    unsigned short* __restrict__ hO) {
  int lane = threadIdx.x & 63;
  int wave = threadIdx.x >> 6;
  int gp = blockIdx.x & 7;            // grp-pair 0..7 (XCD-affine)
  int rblk = blockIdx.x >> 3;         // 0..63
  int tb = (rblk * 4 + wave) * 2;     // row tile base, 0..510
  int m = lane & 15, quad = lane >> 4;

  f32x4 acc[2][2][3];  // [rt][s][gate]
#pragma unroll
  for (int rt = 0; rt < 2; rt++)
#pragma unroll
    for (int s = 0; s < 2; s++)
#pragma unroll
      for (int g = 0; g < 3; g++) acc[rt][s][g] = (f32x4){0.f, 0.f, 0.f, 0.f};

  const unsigned short* ar0 = eb + (tb * 16 + m) * 320 + quad * 8;
  const unsigned short* ar1 = eb + ((tb + 1) * 16 + m) * 320 + quad * 8;
#pragma unroll
  for (int kc = 0; kc < 10; kc++) {
    const unsigned short* bp = Wxf + ((kc * 16 + gp * 2) * 3) * 512 + lane * 8;
    bf16x8 w[6];
#pragma unroll
    for (int i = 0; i < 6; i++) w[i] = *(const bf16x8*)(bp + i * 512);
    bf16x8 a0 = *(const bf16x8*)(ar0 + kc * 32);
    bf16x8 a1 = *(const bf16x8*)(ar1 + kc * 32);
#pragma unroll
    for (int s = 0; s < 2; s++)
#pragma unroll
      for (int g = 0; g < 3; g++) {
        acc[0][s][g] = __builtin_amdgcn_mfma_f32_16x16x32_bf16(a0, w[s * 3 + g], acc[0][s][g], 0, 0, 0);
        acc[1][s][g] = __builtin_amdgcn_mfma_f32_16x16x32_bf16(a1, w[s * 3 + g], acc[1][s][g], 0, 0, 0);
      }
  }
#pragma unroll
  for (int s = 0; s < 2; s++) {
    int col = (gp * 2 + s) * 16 + m;
    float b0 = bx[col], b1 = bx[256 + col], b3 = bx[768 + col];
#pragma unroll
    for (int rt = 0; rt < 2; rt++) {
#pragma unroll
      for (int reg = 0; reg < 4; reg++) {
        int row = (tb + rt) * 16 + quad * 4 + reg;
        float u = tanhf(acc[rt][s][0][reg] + b0);
        float ig = sigf(acc[rt][s][1][reg] + b1);
        float o = sigf(acc[rt][s][2][reg] + b3);
        float c = ig * u;
        cO[row * MEM + col] = c;
        hO[row * MEM + col] = f2b(o * tanhf(c));
      }
    }
  }
}

// ---- Compose: 1-D grid(gx*8); wave = grp-pair x RT row-tiles ----
template <int RT>
__global__ __launch_bounds__(256) void k_compose_mfma(
    const unsigned short* __restrict__ hprev,  // B x 512 bf16 (view)
    const float* __restrict__ cprev,           // 2B x 256 fp32
    const unsigned short* __restrict__ Wcf, const float* __restrict__ bias5,
    float* __restrict__ cO, unsigned short* __restrict__ hO,
    float* __restrict__ hOf,  // non-null on final level: fp32 h out
    int B) {
  int lane = threadIdx.x & 63;
  int wave = threadIdx.x >> 6;
  int gp = blockIdx.x & 7;            // grp-pair (XCD-affine)
  int rblk = blockIdx.x >> 3;
  int tb = (rblk * 4 + wave) * RT;
  if (tb * 16 >= B) return;           // idle wave (no barriers below)
  int m = lane & 15, quad = lane >> 4;
  const bf16x8 zz = {0, 0, 0, 0, 0, 0, 0, 0};

  f32x4 acc[RT][2][5];
  const unsigned short* ar[RT];
  bool ok[RT];
#pragma unroll
  for (int rt = 0; rt < RT; rt++) {
    int ra = (tb + rt) * 16 + m;
    ok[rt] = (ra < B);
    ar[rt] = hprev + ra * 512 + quad * 8;
#pragma unroll
    for (int s = 0; s < 2; s++)
#pragma unroll
      for (int q = 0; q < 5; q++) acc[rt][s][q] = (f32x4){0.f, 0.f, 0.f, 0.f};
  }

#pragma unroll
  for (int kc = 0; kc < 16; kc++) {
    const unsigned short* bp = Wcf + ((kc * 16 + gp * 2) * 5) * 512 + lane * 8;
    bf16x8 w[10];
#pragma unroll
    for (int i = 0; i < 10; i++) w[i] = *(const bf16x8*)(bp + i * 512);
#pragma unroll
    for (int rt = 0; rt < RT; rt++) {
      bf16x8 a = ok[rt] ? *(const bf16x8*)(ar[rt] + kc * 32) : zz;
#pragma unroll
      for (int s = 0; s < 2; s++)
#pragma unroll
        for (int q = 0; q < 5; q++)
          acc[rt][s][q] = __builtin_amdgcn_mfma_f32_16x16x32_bf16(a, w[s * 5 + q], acc[rt][s][q], 0, 0, 0);
    }
  }
#pragma unroll
  for (int s = 0; s < 2; s++) {
    int col = (gp * 2 + s) * 16 + m;
    float b0 = bias5[col], b1 = bias5[256 + col], b2 = bias5[512 + col];
    float b3 = bias5[768 + col], b4 = bias5[1024 + col];
#pragma unroll
    for (int rt = 0; rt < RT; rt++) {
#pragma unroll
      for (int reg = 0; reg < 4; reg++) {
        int row = (tb + rt) * 16 + quad * 4 + reg;
        if (row >= B) continue;
        float u = tanhf(acc[rt][s][0][reg] + b0);
        float ig = sigf(acc[rt][s][1][reg] + b1);
        float lf = sigf(acc[rt][s][2][reg] + b2);
        float rf = sigf(acc[rt][s][3][reg] + b3);
        float o = sigf(acc[rt][s][4][reg] + b4);
        float lc = cprev[(2 * row) * MEM + col];
        float rc = cprev[(2 * row + 1) * MEM + col];
        float c = ig * u + lf * lc + rf * rc;
        float h = o * tanhf(c);
        cO[row * MEM + col] = c;
        hO[row * MEM + col] = f2b(h);
        if (hOf) hOf[row * MEM + col] = h;
      }
    }
  }
}

extern "C" void kernel_launch(void* const* d_in, const int* in_sizes, int n_in,
                              void* d_out, int out_size, void* d_ws, size_t ws_size,
                              hipStream_t stream) {
  const float* embs = (const float*)d_in[0];
  const float* Wx = (const float*)d_in[1];
  const float* bx = (const float*)d_in[2];
  const float* Wl = (const float*)d_in[3];
  const float* Wr = (const float*)d_in[4];
  const float* emb_table = (const float*)d_in[5];
  float* out = (float*)d_out;

  // Workspace layout, ~24.7 MB
  float* ws = (float*)d_ws;
  float* cA = ws;                               // 8192*256 f32
  float* cB = cA + 8192 * 256;                  // 4096*256 f32
  float* bias5 = cB + 4096 * 256;               // 1280 f32
  unsigned short* hA = (unsigned short*)(bias5 + 1280);  // 8192*256 bf16
  unsigned short* hB = hA + 8192 * 256;                  // 4096*256 bf16
  unsigned short* Wcf = hB + 4096 * 256;                 // 1280*512
  unsigned short* Wxf = Wcf + 1280 * 512;                // 480*512
  unsigned short* eb = Wxf + 480 * 512;                  // 8192*320

  // Fused one-time prep (13765 blocks)
  k_prep<<<NB_WCF + NB_WXF + NB_EB + 5, 256, 0, stream>>>(
      Wl, Wr, Wx, bx, embs, emb_table + (in_sizes[5] - 300),
      Wcf, Wxf, eb, bias5);

  // Leaf level -> cA (f32), hA (bf16); RT=2, BN=32
  k_leaf_mfma<<<512, 256, 0, stream>>>(eb, Wxf, bx, cA, hA);

  // 13 tree levels, per-level launches
  const float* cs = cA;
  const unsigned short* hs = hA;
  int B = 4096;
  int lvl = 0;
  while (B >= 1) {
    float* dc;
    unsigned short* dh;
    float* dhf = nullptr;
    if (B == 1) {
      dc = out;
      dh = hB;  // dummy bf16 sink
      dhf = out + 256;
    } else if ((lvl & 1) == 0) {
      dc = cB; dh = hB;
    } else {
      dc = cA; dh = hA;
    }
    int tiles = (B + 15) / 16;
    if (B == 4096) {
      // RT=2: gx = 256/8 = 32 -> 256 blocks
      k_compose_mfma<2><<<32 * 8, 256, 0, stream>>>(
          hs, cs, Wcf, bias5, dc, dh, dhf, B);
    } else {
      int gx = (tiles + 3) / 4;
      k_compose_mfma<1><<<gx * 8, 256, 0, stream>>>(
          hs, cs, Wcf, bias5, dc, dh, dhf, B);
    }
    cs = dc;
    hs = dh;
    B >>= 1;
    lvl++;
  }
}

// Round 4
// 265.106 us; speedup vs baseline: 1.0945x; 1.0945x over previous
//
#include <hip/hip_runtime.h>
#include <hip/hip_bf16.h>
#include <math.h>

// BinaryTreeLSTM on MI355X — R7.
// vs R6 (290us): REVERT BN=32 (fat waves cut occupancy; latency-bound regime
// -> keep R5 grids, 261us baseline). New:
//  (1) prep+leaf FUSED into one kernel: leaf blocks read embs/Wx f32 directly
//      with inline f32->bf16 (scalar cast -> cvt_pk). Removes eb (15MB/iter),
//      Wxf, and one launch.
//  (2) K-split compose for B<=32 (6 levels): 4 waves x 4 kc each + LDS
//      reduce — was 1-2 active waves with 16-kc serial chains.
// Dispatches: fused(prep+leaf), compose x7 (4096..64), ksplit x6 (32..1) = 14.

#define MEM 256

typedef __attribute__((ext_vector_type(8))) short bf16x8;
typedef __attribute__((ext_vector_type(4))) float f32x4;

__device__ __forceinline__ float sigf(float x) { return 1.0f / (1.0f + __expf(-x)); }

__device__ __forceinline__ unsigned short f2b(float f) {
  unsigned int u = __float_as_uint(f);
  u = (u + 0x7FFFu + ((u >> 16) & 1u)) >> 16;
  return (unsigned short)u;
}

__device__ __forceinline__ unsigned short cvt1(float f) {
  __hip_bfloat16 b = __float2bfloat16(f);  // RNE; compiler emits cvt_pk pairs
  return *reinterpret_cast<unsigned short*>(&b);
}

// Gather 8 consecutive k-elements (f32, row length 300, zero-pad) -> bf16x8
__device__ __forceinline__ bf16x8 gather8(const float* __restrict__ rowp, int k0) {
  bf16x8 r;
  if (k0 + 8 <= 300) {
    const float4 f0 = *(const float4*)(rowp + k0);
    const float4 f1 = *(const float4*)(rowp + k0 + 4);
    r[0] = cvt1(f0.x); r[1] = cvt1(f0.y); r[2] = cvt1(f0.z); r[3] = cvt1(f0.w);
    r[4] = cvt1(f1.x); r[5] = cvt1(f1.y); r[6] = cvt1(f1.z); r[7] = cvt1(f1.w);
  } else {
#pragma unroll
    for (int j = 0; j < 8; j++) {
      int k = k0 + j;
      r[j] = (k < 300) ? (short)cvt1(rowp[k]) : (short)0;
    }
  }
  return r;
}

// ---- Fused: leaf (blocks 0..1023) | Wcf shuffle (1024..3583) | bias5 (3584..3588)
#define NB_LEAF 1024
#define NB_WCF 2560
__global__ __launch_bounds__(256) void k_fused(
    const float* __restrict__ embs, const float* __restrict__ Wx,
    const float* __restrict__ bx, const float* __restrict__ Wl,
    const float* __restrict__ Wr, const float* __restrict__ emb_last,
    unsigned short* __restrict__ Wcf, float* __restrict__ bias5,
    float* __restrict__ cO, unsigned short* __restrict__ hO) {
  int b = blockIdx.x;
  int tid = threadIdx.x;
  if (b < NB_LEAF) {
    // ---- leaf role: grp = b&15, rblk = b>>4; wave = 2 row tiles ----
    int grp = b & 15, rblk = b >> 4;
    int lane = tid & 63, wave = tid >> 6;
    int tb = (rblk * 4 + wave) * 2;  // 0..510
    int m = lane & 15, quad = lane >> 4;
    const int gmap[3] = {0, 1, 3};

    f32x4 acc[2][3];
#pragma unroll
    for (int rt = 0; rt < 2; rt++)
#pragma unroll
      for (int g = 0; g < 3; g++) acc[rt][g] = (f32x4){0.f, 0.f, 0.f, 0.f};

    const float* ar0 = embs + (tb * 16 + m) * 300;
    const float* ar1 = embs + ((tb + 1) * 16 + m) * 300;
    const float* wr0 = Wx + (gmap[0] * 256 + grp * 16 + m) * 300;
    const float* wr1 = Wx + (gmap[1] * 256 + grp * 16 + m) * 300;
    const float* wr2 = Wx + (gmap[2] * 256 + grp * 16 + m) * 300;
#pragma unroll
    for (int kc = 0; kc < 10; kc++) {
      int k0 = kc * 32 + quad * 8;
      bf16x8 a0 = gather8(ar0, k0);
      bf16x8 a1 = gather8(ar1, k0);
      bf16x8 w0 = gather8(wr0, k0);
      acc[0][0] = __builtin_amdgcn_mfma_f32_16x16x32_bf16(a0, w0, acc[0][0], 0, 0, 0);
      acc[1][0] = __builtin_amdgcn_mfma_f32_16x16x32_bf16(a1, w0, acc[1][0], 0, 0, 0);
      bf16x8 w1 = gather8(wr1, k0);
      acc[0][1] = __builtin_amdgcn_mfma_f32_16x16x32_bf16(a0, w1, acc[0][1], 0, 0, 0);
      acc[1][1] = __builtin_amdgcn_mfma_f32_16x16x32_bf16(a1, w1, acc[1][1], 0, 0, 0);
      bf16x8 w2 = gather8(wr2, k0);
      acc[0][2] = __builtin_amdgcn_mfma_f32_16x16x32_bf16(a0, w2, acc[0][2], 0, 0, 0);
      acc[1][2] = __builtin_amdgcn_mfma_f32_16x16x32_bf16(a1, w2, acc[1][2], 0, 0, 0);
    }
    int col = grp * 16 + m;
    float b0 = bx[col], b1 = bx[256 + col], b3 = bx[768 + col];
#pragma unroll
    for (int rt = 0; rt < 2; rt++) {
#pragma unroll
      for (int reg = 0; reg < 4; reg++) {
        int row = (tb + rt) * 16 + quad * 4 + reg;
        float u = tanhf(acc[rt][0][reg] + b0);
        float ig = sigf(acc[rt][1][reg] + b1);
        float o = sigf(acc[rt][2][reg] + b3);
        float c = ig * u;
        cO[row * MEM + col] = c;
        hO[row * MEM + col] = f2b(o * tanhf(c));
      }
    }
  } else if (b < NB_LEAF + NB_WCF) {
    // ---- Wcf shuffle role ----
    int idx = (b - NB_LEAF) * 256 + tid;  // 1280*512
    int f = idx >> 9, r = idx & 511;
    int lane = r >> 3, j = r & 7;
    int gate = f % 5, t = f / 5;
    int grp = t & 15, kc = t >> 4;
    int k = kc * 32 + ((lane >> 4) << 3) + j;
    int n = gate * 256 + (grp << 4) + (lane & 15);
    float v = (k < 256) ? Wl[n * 256 + k] : Wr[n * 256 + (k - 256)];
    Wcf[idx] = f2b(v);
  } else {
    // ---- bias5 role (5 blocks) ----
    int g = b - (NB_LEAF + NB_WCF);  // 0..4
    __shared__ float er[300];
    for (int k = tid; k < 300; k += 256) er[k] = emb_last[k];
    __syncthreads();
    const int map[5] = {0, 1, 2, 2, 3};
    int wrow = map[g] * 256 + tid;
    const float* w = Wx + wrow * 300;
    float s = bx[wrow];
    for (int k = 0; k < 300; k++) s += er[k] * w[k];
    bias5[g * 256 + tid] = s;
  }
}

// ---- Compose: template RT row-tiles per wave; grid(ceil(tiles/(4*RT)),16) ----
template <int RT>
__global__ __launch_bounds__(256) void k_compose_mfma(
    const unsigned short* __restrict__ hprev,  // B x 512 bf16 (view)
    const float* __restrict__ cprev,           // 2B x 256 fp32
    const unsigned short* __restrict__ Wcf, const float* __restrict__ bias5,
    float* __restrict__ cO, unsigned short* __restrict__ hO,
    float* __restrict__ hOf, int B) {
  int lane = threadIdx.x & 63;
  int wave = threadIdx.x >> 6;
  int grp = blockIdx.y;                       // 0..15
  int tb = (blockIdx.x * 4 + wave) * RT;      // row tile base
  if (tb * 16 >= B) return;                   // idle wave (no barriers below)
  int m = lane & 15, quad = lane >> 4;
  const bf16x8 zz = {0, 0, 0, 0, 0, 0, 0, 0};

  f32x4 acc[RT][5];
  const unsigned short* ar[RT];
  bool ok[RT];
#pragma unroll
  for (int rt = 0; rt < RT; rt++) {
    int ra = (tb + rt) * 16 + m;
    ok[rt] = (ra < B);
    ar[rt] = hprev + ra * 512 + quad * 8;
#pragma unroll
    for (int g = 0; g < 5; g++) acc[rt][g] = (f32x4){0.f, 0.f, 0.f, 0.f};
  }

#pragma unroll
  for (int kc = 0; kc < 16; kc++) {
    const unsigned short* bp = Wcf + ((kc * 16 + grp) * 5) * 512 + lane * 8;
    bf16x8 b0 = *(const bf16x8*)(bp);
    bf16x8 b1 = *(const bf16x8*)(bp + 512);
    bf16x8 b2 = *(const bf16x8*)(bp + 1024);
    bf16x8 b3 = *(const bf16x8*)(bp + 1536);
    bf16x8 b4 = *(const bf16x8*)(bp + 2048);
#pragma unroll
    for (int rt = 0; rt < RT; rt++) {
      bf16x8 a = ok[rt] ? *(const bf16x8*)(ar[rt] + kc * 32) : zz;
      acc[rt][0] = __builtin_amdgcn_mfma_f32_16x16x32_bf16(a, b0, acc[rt][0], 0, 0, 0);
      acc[rt][1] = __builtin_amdgcn_mfma_f32_16x16x32_bf16(a, b1, acc[rt][1], 0, 0, 0);
      acc[rt][2] = __builtin_amdgcn_mfma_f32_16x16x32_bf16(a, b2, acc[rt][2], 0, 0, 0);
      acc[rt][3] = __builtin_amdgcn_mfma_f32_16x16x32_bf16(a, b3, acc[rt][3], 0, 0, 0);
      acc[rt][4] = __builtin_amdgcn_mfma_f32_16x16x32_bf16(a, b4, acc[rt][4], 0, 0, 0);
    }
  }
  int col = grp * 16 + m;
  float b0 = bias5[col], b1 = bias5[256 + col], b2 = bias5[512 + col];
  float b3 = bias5[768 + col], b4 = bias5[1024 + col];
#pragma unroll
  for (int rt = 0; rt < RT; rt++) {
#pragma unroll
    for (int reg = 0; reg < 4; reg++) {
      int row = (tb + rt) * 16 + quad * 4 + reg;
      if (row >= B) continue;
      float u = tanhf(acc[rt][0][reg] + b0);
      float ig = sigf(acc[rt][1][reg] + b1);
      float lf = sigf(acc[rt][2][reg] + b2);
      float rf = sigf(acc[rt][3][reg] + b3);
      float o = sigf(acc[rt][4][reg] + b4);
      float lc = cprev[(2 * row) * MEM + col];
      float rc = cprev[(2 * row + 1) * MEM + col];
      float c = ig * u + lf * lc + rf * rc;
      float h = o * tanhf(c);
      cO[row * MEM + col] = c;
      hO[row * MEM + col] = f2b(h);
      if (hOf) hOf[row * MEM + col] = h;
    }
  }
}

// ---- K-split compose for B<=32: grid(1,16); 4 waves x 4 kc; LDS reduce ----
__global__ __launch_bounds__(256) void k_compose_ksplit(
    const unsigned short* __restrict__ hprev, const float* __restrict__ cprev,
    const unsigned short* __restrict__ Wcf, const float* __restrict__ bias5,
    float* __restrict__ cO, unsigned short* __restrict__ hO,
    float* __restrict__ hOf, int B) {
  __shared__ __align__(16) float lds[4 * 2 * 5 * 64 * 4];  // 40KB
  int tid = threadIdx.x;
  int lane = tid & 63, wave = tid >> 6;
  int grp = blockIdx.y;
  int m = lane & 15, quad = lane >> 4;
  int tiles = (B + 15) >> 4;  // 1 or 2
  const bf16x8 zz = {0, 0, 0, 0, 0, 0, 0, 0};

  f32x4 acc[2][5];
  bool ok[2];
  const unsigned short* ar[2];
#pragma unroll
  for (int t = 0; t < 2; t++) {
    int ra = t * 16 + m;
    ok[t] = (t < tiles) && (ra < B);
    ar[t] = hprev + ra * 512 + quad * 8;
#pragma unroll
    for (int q = 0; q < 5; q++) acc[t][q] = (f32x4){0.f, 0.f, 0.f, 0.f};
  }

#pragma unroll
  for (int kcl = 0; kcl < 4; kcl++) {
    int kc = wave * 4 + kcl;
    const unsigned short* bp = Wcf + ((kc * 16 + grp) * 5) * 512 + lane * 8;
    bf16x8 b0 = *(const bf16x8*)(bp);
    bf16x8 b1 = *(const bf16x8*)(bp + 512);
    bf16x8 b2 = *(const bf16x8*)(bp + 1024);
    bf16x8 b3 = *(const bf16x8*)(bp + 1536);
    bf16x8 b4 = *(const bf16x8*)(bp + 2048);
#pragma unroll
    for (int t = 0; t < 2; t++) {
      if (t < tiles) {
        bf16x8 a = ok[t] ? *(const bf16x8*)(ar[t] + kc * 32) : zz;
        acc[t][0] = __builtin_amdgcn_mfma_f32_16x16x32_bf16(a, b0, acc[t][0], 0, 0, 0);
        acc[t][1] = __builtin_amdgcn_mfma_f32_16x16x32_bf16(a, b1, acc[t][1], 0, 0, 0);
        acc[t][2] = __builtin_amdgcn_mfma_f32_16x16x32_bf16(a, b2, acc[t][2], 0, 0, 0);
        acc[t][3] = __builtin_amdgcn_mfma_f32_16x16x32_bf16(a, b3, acc[t][3], 0, 0, 0);
        acc[t][4] = __builtin_amdgcn_mfma_f32_16x16x32_bf16(a, b4, acc[t][4], 0, 0, 0);
      }
    }
  }
  // store partials: [wave][t][q][lane] f32x4
#pragma unroll
  for (int t = 0; t < 2; t++)
    if (t < tiles)
#pragma unroll
      for (int q = 0; q < 5; q++)
        *(f32x4*)&lds[(((wave * 2 + t) * 5 + q) * 64 + lane) * 4] = acc[t][q];
  __syncthreads();

  if (wave < tiles) {
    int t = wave;
    int col = grp * 16 + m;
    float b0 = bias5[col], b1 = bias5[256 + col], b2 = bias5[512 + col];
    float b3 = bias5[768 + col], b4 = bias5[1024 + col];
    f32x4 s[5];
#pragma unroll
    for (int q = 0; q < 5; q++) {
      s[q] = *(const f32x4*)&lds[(((0 * 2 + t) * 5 + q) * 64 + lane) * 4];
#pragma unroll
      for (int v = 1; v < 4; v++) {
        f32x4 p = *(const f32x4*)&lds[(((v * 2 + t) * 5 + q) * 64 + lane) * 4];
        s[q][0] += p[0]; s[q][1] += p[1]; s[q][2] += p[2]; s[q][3] += p[3];
      }
    }
#pragma unroll
    for (int reg = 0; reg < 4; reg++) {
      int row = t * 16 + quad * 4 + reg;
      if (row >= B) continue;
      float u = tanhf(s[0][reg] + b0);
      float ig = sigf(s[1][reg] + b1);
      float lf = sigf(s[2][reg] + b2);
      float rf = sigf(s[3][reg] + b3);
      float o = sigf(s[4][reg] + b4);
      float lc = cprev[(2 * row) * MEM + col];
      float rc = cprev[(2 * row + 1) * MEM + col];
      float c = ig * u + lf * lc + rf * rc;
      float h = o * tanhf(c);
      cO[row * MEM + col] = c;
      hO[row * MEM + col] = f2b(h);
      if (hOf) hOf[row * MEM + col] = h;
    }
  }
}

extern "C" void kernel_launch(void* const* d_in, const int* in_sizes, int n_in,
                              void* d_out, int out_size, void* d_ws, size_t ws_size,
                              hipStream_t stream) {
  const float* embs = (const float*)d_in[0];
  const float* Wx = (const float*)d_in[1];
  const float* bx = (const float*)d_in[2];
  const float* Wl = (const float*)d_in[3];
  const float* Wr = (const float*)d_in[4];
  const float* emb_table = (const float*)d_in[5];
  float* out = (float*)d_out;

  // Workspace layout (~19 MB)
  float* ws = (float*)d_ws;
  float* cA = ws;                               // 8192*256 f32
  float* cB = cA + 8192 * 256;                  // 4096*256 f32
  float* bias5 = cB + 4096 * 256;               // 1280 f32
  unsigned short* hA = (unsigned short*)(bias5 + 1280);  // 8192*256 bf16
  unsigned short* hB = hA + 8192 * 256;                  // 4096*256 bf16
  unsigned short* Wcf = hB + 4096 * 256;                 // 1280*512

  // Fused prep + leaf (3589 blocks): leaf -> cA (f32), hA (bf16)
  k_fused<<<NB_LEAF + NB_WCF + 5, 256, 0, stream>>>(
      embs, Wx, bx, Wl, Wr, emb_table + (in_sizes[5] - 300),
      Wcf, bias5, cA, hA);

  // 13 tree levels
  const float* cs = cA;
  const unsigned short* hs = hA;
  int B = 4096;
  int lvl = 0;
  while (B >= 1) {
    float* dc;
    unsigned short* dh;
    float* dhf = nullptr;
    if (B == 1) {
      dc = out;
      dh = hB;  // dummy bf16 sink
      dhf = out + 256;
    } else if ((lvl & 1) == 0) {
      dc = cB; dh = hB;
    } else {
      dc = cA; dh = hA;
    }
    int tiles = (B + 15) / 16;
    if (B == 4096) {
      k_compose_mfma<2><<<dim3(tiles / 8, 16), 256, 0, stream>>>(
          hs, cs, Wcf, bias5, dc, dh, dhf, B);
    } else if (B >= 64) {
      int gx = (tiles + 3) / 4;
      k_compose_mfma<1><<<dim3(gx, 16), 256, 0, stream>>>(
          hs, cs, Wcf, bias5, dc, dh, dhf, B);
    } else {
      k_compose_ksplit<<<dim3(1, 16), 256, 0, stream>>>(
          hs, cs, Wcf, bias5, dc, dh, dhf, B);
    }
    cs = dc;
    hs = dh;
    B >>= 1;
    lvl++;
  }
}

// Round 5
// 249.321 us; speedup vs baseline: 1.1638x; 1.0633x over previous
//
#include <hip/hip_runtime.h>
#include <math.h>

// BinaryTreeLSTM on MI355X — R8.
// vs R7 (265us; k_fused measured 60us, 44MB fetch, latency-bound):
//  (1) Restore two-stage front-end: prep converts embs->eb bf16 (leaf reads
//      bf16, no cvt in loop, half the bytes). Prep fully vectorized:
//      bf16x8 loads/stores, 1725 blocks (was 13765 / was fused-direct-f32).
//  (2) XCD row-affinity: 1-D grids; slice = bid%8 owns a contiguous row
//      range. Per-XCD working set (h-slice + c-slice + full weights) fits
//      4MB L2 at B=4096; level l slice s writes exactly what level l+1
//      slice s reads -> cross-kernel L2 reuse. Per-wave shape unchanged
//      (R6 lesson: don't trade occupancy for density).
//  (3) Keep R7 ksplit for B<=32.
// Dispatches: prep, leaf, compose x7 (4096..64), ksplit x6 (32..1) = 15.

#define MEM 256

typedef __attribute__((ext_vector_type(8))) short bf16x8;
typedef __attribute__((ext_vector_type(4))) float f32x4;

__device__ __forceinline__ float sigf(float x) { return 1.0f / (1.0f + __expf(-x)); }

__device__ __forceinline__ unsigned short f2b(float f) {
  unsigned int u = __float_as_uint(f);
  u = (u + 0x7FFFu + ((u >> 16) & 1u)) >> 16;
  return (unsigned short)u;
}

// 8 consecutive f32 -> bf16x8 (no bounds concern)
__device__ __forceinline__ bf16x8 c8(const float* __restrict__ p) {
  float4 f0 = *(const float4*)(p);
  float4 f1 = *(const float4*)(p + 4);
  bf16x8 r;
  r[0] = (short)f2b(f0.x); r[1] = (short)f2b(f0.y);
  r[2] = (short)f2b(f0.z); r[3] = (short)f2b(f0.w);
  r[4] = (short)f2b(f1.x); r[5] = (short)f2b(f1.y);
  r[6] = (short)f2b(f1.z); r[7] = (short)f2b(f1.w);
  return r;
}

// 8 consecutive k from a 300-long f32 row, zero-padded past 300
__device__ __forceinline__ bf16x8 g8(const float* __restrict__ rp, int k0) {
  if (k0 + 8 <= 300) return c8(rp + k0);
  bf16x8 r;
#pragma unroll
  for (int j = 0; j < 8; j++) {
    int k = k0 + j;
    r[j] = (k < 300) ? (short)f2b(rp[k]) : (short)0;
  }
  return r;
}

// ---- Prep (vectorized): eb | Wcf | Wxf | bias5 ----
#define NB_EB 1280   // 8192*320/2048
#define NB_WCF 320   // 1280*512/2048
#define NB_WXF 120   // 480*512/2048
__global__ __launch_bounds__(256) void k_prep(
    const float* __restrict__ embs, const float* __restrict__ Wx,
    const float* __restrict__ bx, const float* __restrict__ Wl,
    const float* __restrict__ Wr, const float* __restrict__ emb_last,
    unsigned short* __restrict__ eb, unsigned short* __restrict__ Wcf,
    unsigned short* __restrict__ Wxf, float* __restrict__ bias5) {
  int b = blockIdx.x, tid = threadIdx.x;
  if (b < NB_EB) {
    int idx8 = (b * 256 + tid) * 8;       // 8192*320
    int row = idx8 / 320;
    int k0 = idx8 - row * 320;            // multiple of 8
    *(bf16x8*)(eb + idx8) = g8(embs + row * 300, k0);
  } else if (b < NB_EB + NB_WCF) {
    int idx8 = ((b - NB_EB) * 256 + tid) * 8;  // 1280*512
    int f = idx8 >> 9, rr = idx8 & 511;
    int lane = rr >> 3;
    int gate = f % 5, t = f / 5;
    int grp = t & 15, kc = t >> 4;
    int k0 = kc * 32 + ((lane >> 4) << 3);  // mult of 8; 8-run never straddles 256
    int n = gate * 256 + (grp << 4) + (lane & 15);
    const float* src = (k0 < 256) ? (Wl + n * 256 + k0) : (Wr + n * 256 + (k0 - 256));
    *(bf16x8*)(Wcf + idx8) = c8(src);
  } else if (b < NB_EB + NB_WCF + NB_WXF) {
    int idx8 = ((b - NB_EB - NB_WCF) * 256 + tid) * 8;  // 480*512
    int f = idx8 >> 9, rr = idx8 & 511;
    int lane = rr >> 3;
    int gate = f % 3, t = f / 3;
    int grp = t & 15, kc = t >> 4;
    int k0 = kc * 32 + ((lane >> 4) << 3);
    const int gmap[3] = {0, 1, 3};
    int n = gmap[gate] * 256 + (grp << 4) + (lane & 15);
    *(bf16x8*)(Wxf + idx8) = g8(Wx + n * 300, k0);
  } else {
    int g = b - (NB_EB + NB_WCF + NB_WXF);  // 0..4
    __shared__ float er[300];
    for (int k = tid; k < 300; k += 256) er[k] = emb_last[k];
    __syncthreads();
    const int map[5] = {0, 1, 2, 2, 3};
    int wrow = map[g] * 256 + tid;
    const float* w = Wx + wrow * 300;
    float s = bx[wrow];
    for (int k = 0; k < 300; k++) s += er[k] * w[k];
    bias5[g * 256 + tid] = s;
  }
}

// ---- Leaf: 1-D grid(1024); slice=bid&7 row-affine; wave = 2 row tiles ----
__global__ __launch_bounds__(256) void k_leaf_mfma(
    const unsigned short* __restrict__ eb, const unsigned short* __restrict__ Wxf,
    const float* __restrict__ bx, float* __restrict__ cO,
    unsigned short* __restrict__ hO) {
  int bid = blockIdx.x;
  int slice = bid & 7, rest = bid >> 3;     // rest 0..127
  int rowblock = slice * 8 + (rest & 7);    // 0..63, contiguous per slice
  int grp = rest >> 3;                      // 0..15
  int lane = threadIdx.x & 63;
  int wave = threadIdx.x >> 6;
  int tb = (rowblock * 4 + wave) * 2;       // 0..510
  int m = lane & 15, quad = lane >> 4;

  f32x4 acc[2][3];
#pragma unroll
  for (int rt = 0; rt < 2; rt++)
#pragma unroll
    for (int g = 0; g < 3; g++) acc[rt][g] = (f32x4){0.f, 0.f, 0.f, 0.f};

  const unsigned short* ar0 = eb + (tb * 16 + m) * 320 + quad * 8;
  const unsigned short* ar1 = eb + ((tb + 1) * 16 + m) * 320 + quad * 8;
#pragma unroll
  for (int kc = 0; kc < 10; kc++) {
    const unsigned short* bp = Wxf + ((kc * 16 + grp) * 3) * 512 + lane * 8;
    bf16x8 b0 = *(const bf16x8*)(bp);
    bf16x8 b1 = *(const bf16x8*)(bp + 512);
    bf16x8 b2 = *(const bf16x8*)(bp + 1024);
    bf16x8 a0 = *(const bf16x8*)(ar0 + kc * 32);
    bf16x8 a1 = *(const bf16x8*)(ar1 + kc * 32);
    acc[0][0] = __builtin_amdgcn_mfma_f32_16x16x32_bf16(a0, b0, acc[0][0], 0, 0, 0);
    acc[0][1] = __builtin_amdgcn_mfma_f32_16x16x32_bf16(a0, b1, acc[0][1], 0, 0, 0);
    acc[0][2] = __builtin_amdgcn_mfma_f32_16x16x32_bf16(a0, b2, acc[0][2], 0, 0, 0);
    acc[1][0] = __builtin_amdgcn_mfma_f32_16x16x32_bf16(a1, b0, acc[1][0], 0, 0, 0);
    acc[1][1] = __builtin_amdgcn_mfma_f32_16x16x32_bf16(a1, b1, acc[1][1], 0, 0, 0);
    acc[1][2] = __builtin_amdgcn_mfma_f32_16x16x32_bf16(a1, b2, acc[1][2], 0, 0, 0);
  }
  int col = grp * 16 + m;
  float b0 = bx[col], b1 = bx[256 + col], b3 = bx[768 + col];
#pragma unroll
  for (int rt = 0; rt < 2; rt++) {
#pragma unroll
    for (int reg = 0; reg < 4; reg++) {
      int row = (tb + rt) * 16 + quad * 4 + reg;
      float u = tanhf(acc[rt][0][reg] + b0);
      float ig = sigf(acc[rt][1][reg] + b1);
      float o = sigf(acc[rt][2][reg] + b3);
      float c = ig * u;
      cO[row * MEM + col] = c;
      hO[row * MEM + col] = f2b(o * tanhf(c));
    }
  }
}

// ---- Compose: 1-D grid(gx*16), row-affine slices; RT row-tiles per wave ----
template <int RT>
__global__ __launch_bounds__(256) void k_compose_mfma(
    const unsigned short* __restrict__ hprev,  // B x 512 bf16 (view)
    const float* __restrict__ cprev,           // 2B x 256 fp32
    const unsigned short* __restrict__ Wcf, const float* __restrict__ bias5,
    float* __restrict__ cO, unsigned short* __restrict__ hO,
    float* __restrict__ hOf, int B) {
  int tiles = B >> 4;
  int gx = tiles / (4 * RT);               // exact (B>=64, powers of two)
  int S = gx >= 8 ? 8 : gx;
  int pc = gx / S;
  int bid = blockIdx.x;
  int slice = bid % S;
  int rest = bid / S;
  int rowblock = slice * pc + rest % pc;   // contiguous rows per slice
  int grp = rest / pc;                     // 0..15
  int lane = threadIdx.x & 63;
  int wave = threadIdx.x >> 6;
  int tb = (rowblock * 4 + wave) * RT;
  if (tb * 16 >= B) return;
  int m = lane & 15, quad = lane >> 4;
  const bf16x8 zz = {0, 0, 0, 0, 0, 0, 0, 0};

  f32x4 acc[RT][5];
  const unsigned short* ar[RT];
  bool ok[RT];
#pragma unroll
  for (int rt = 0; rt < RT; rt++) {
    int ra = (tb + rt) * 16 + m;
    ok[rt] = (ra < B);
    ar[rt] = hprev + ra * 512 + quad * 8;
#pragma unroll
    for (int g = 0; g < 5; g++) acc[rt][g] = (f32x4){0.f, 0.f, 0.f, 0.f};
  }

#pragma unroll
  for (int kc = 0; kc < 16; kc++) {
    const unsigned short* bp = Wcf + ((kc * 16 + grp) * 5) * 512 + lane * 8;
    bf16x8 b0 = *(const bf16x8*)(bp);
    bf16x8 b1 = *(const bf16x8*)(bp + 512);
    bf16x8 b2 = *(const bf16x8*)(bp + 1024);
    bf16x8 b3 = *(const bf16x8*)(bp + 1536);
    bf16x8 b4 = *(const bf16x8*)(bp + 2048);
#pragma unroll
    for (int rt = 0; rt < RT; rt++) {
      bf16x8 a = ok[rt] ? *(const bf16x8*)(ar[rt] + kc * 32) : zz;
      acc[rt][0] = __builtin_amdgcn_mfma_f32_16x16x32_bf16(a, b0, acc[rt][0], 0, 0, 0);
      acc[rt][1] = __builtin_amdgcn_mfma_f32_16x16x32_bf16(a, b1, acc[rt][1], 0, 0, 0);
      acc[rt][2] = __builtin_amdgcn_mfma_f32_16x16x32_bf16(a, b2, acc[rt][2], 0, 0, 0);
      acc[rt][3] = __builtin_amdgcn_mfma_f32_16x16x32_bf16(a, b3, acc[rt][3], 0, 0, 0);
      acc[rt][4] = __builtin_amdgcn_mfma_f32_16x16x32_bf16(a, b4, acc[rt][4], 0, 0, 0);
    }
  }
  int col = grp * 16 + m;
  float b0 = bias5[col], b1 = bias5[256 + col], b2 = bias5[512 + col];
  float b3 = bias5[768 + col], b4 = bias5[1024 + col];
#pragma unroll
  for (int rt = 0; rt < RT; rt++) {
#pragma unroll
    for (int reg = 0; reg < 4; reg++) {
      int row = (tb + rt) * 16 + quad * 4 + reg;
      if (row >= B) continue;
      float u = tanhf(acc[rt][0][reg] + b0);
      float ig = sigf(acc[rt][1][reg] + b1);
      float lf = sigf(acc[rt][2][reg] + b2);
      float rf = sigf(acc[rt][3][reg] + b3);
      float o = sigf(acc[rt][4][reg] + b4);
      float lc = cprev[(2 * row) * MEM + col];
      float rc = cprev[(2 * row + 1) * MEM + col];
      float c = ig * u + lf * lc + rf * rc;
      float h = o * tanhf(c);
      cO[row * MEM + col] = c;
      hO[row * MEM + col] = f2b(h);
      if (hOf) hOf[row * MEM + col] = h;
    }
  }
}

// ---- K-split compose for B<=32: grid(1,16); 4 waves x 4 kc; LDS reduce ----
__global__ __launch_bounds__(256) void k_compose_ksplit(
    const unsigned short* __restrict__ hprev, const float* __restrict__ cprev,
    const unsigned short* __restrict__ Wcf, const float* __restrict__ bias5,
    float* __restrict__ cO, unsigned short* __restrict__ hO,
    float* __restrict__ hOf, int B) {
  __shared__ __align__(16) float lds[4 * 2 * 5 * 64 * 4];  // 40KB
  int tid = threadIdx.x;
  int lane = tid & 63, wave = tid >> 6;
  int grp = blockIdx.y;
  int m = lane & 15, quad = lane >> 4;
  int tiles = (B + 15) >> 4;  // 1 or 2
  const bf16x8 zz = {0, 0, 0, 0, 0, 0, 0, 0};

  f32x4 acc[2][5];
  bool ok[2];
  const unsigned short* ar[2];
#pragma unroll
  for (int t = 0; t < 2; t++) {
    int ra = t * 16 + m;
    ok[t] = (t < tiles) && (ra < B);
    ar[t] = hprev + ra * 512 + quad * 8;
#pragma unroll
    for (int q = 0; q < 5; q++) acc[t][q] = (f32x4){0.f, 0.f, 0.f, 0.f};
  }

#pragma unroll
  for (int kcl = 0; kcl < 4; kcl++) {
    int kc = wave * 4 + kcl;
    const unsigned short* bp = Wcf + ((kc * 16 + grp) * 5) * 512 + lane * 8;
    bf16x8 b0 = *(const bf16x8*)(bp);
    bf16x8 b1 = *(const bf16x8*)(bp + 512);
    bf16x8 b2 = *(const bf16x8*)(bp + 1024);
    bf16x8 b3 = *(const bf16x8*)(bp + 1536);
    bf16x8 b4 = *(const bf16x8*)(bp + 2048);
#pragma unroll
    for (int t = 0; t < 2; t++) {
      if (t < tiles) {
        bf16x8 a = ok[t] ? *(const bf16x8*)(ar[t] + kc * 32) : zz;
        acc[t][0] = __builtin_amdgcn_mfma_f32_16x16x32_bf16(a, b0, acc[t][0], 0, 0, 0);
        acc[t][1] = __builtin_amdgcn_mfma_f32_16x16x32_bf16(a, b1, acc[t][1], 0, 0, 0);
        acc[t][2] = __builtin_amdgcn_mfma_f32_16x16x32_bf16(a, b2, acc[t][2], 0, 0, 0);
        acc[t][3] = __builtin_amdgcn_mfma_f32_16x16x32_bf16(a, b3, acc[t][3], 0, 0, 0);
        acc[t][4] = __builtin_amdgcn_mfma_f32_16x16x32_bf16(a, b4, acc[t][4], 0, 0, 0);
      }
    }
  }
#pragma unroll
  for (int t = 0; t < 2; t++)
    if (t < tiles)
#pragma unroll
      for (int q = 0; q < 5; q++)
        *(f32x4*)&lds[(((wave * 2 + t) * 5 + q) * 64 + lane) * 4] = acc[t][q];
  __syncthreads();

  if (wave < tiles) {
    int t = wave;
    int col = grp * 16 + m;
    float b0 = bias5[col], b1 = bias5[256 + col], b2 = bias5[512 + col];
    float b3 = bias5[768 + col], b4 = bias5[1024 + col];
    f32x4 s[5];
#pragma unroll
    for (int q = 0; q < 5; q++) {
      s[q] = *(const f32x4*)&lds[(((0 * 2 + t) * 5 + q) * 64 + lane) * 4];
#pragma unroll
      for (int v = 1; v < 4; v++) {
        f32x4 p = *(const f32x4*)&lds[(((v * 2 + t) * 5 + q) * 64 + lane) * 4];
        s[q][0] += p[0]; s[q][1] += p[1]; s[q][2] += p[2]; s[q][3] += p[3];
      }
    }
#pragma unroll
    for (int reg = 0; reg < 4; reg++) {
      int row = t * 16 + quad * 4 + reg;
      if (row >= B) continue;
      float u = tanhf(s[0][reg] + b0);
      float ig = sigf(s[1][reg] + b1);
      float lf = sigf(s[2][reg] + b2);
      float rf = sigf(s[3][reg] + b3);
      float o = sigf(s[4][reg] + b4);
      float lc = cprev[(2 * row) * MEM + col];
      float rc = cprev[(2 * row + 1) * MEM + col];
      float c = ig * u + lf * lc + rf * rc;
      float h = o * tanhf(c);
      cO[row * MEM + col] = c;
      hO[row * MEM + col] = f2b(h);
      if (hOf) hOf[row * MEM + col] = h;
    }
  }
}

extern "C" void kernel_launch(void* const* d_in, const int* in_sizes, int n_in,
                              void* d_out, int out_size, void* d_ws, size_t ws_size,
                              hipStream_t stream) {
  const float* embs = (const float*)d_in[0];
  const float* Wx = (const float*)d_in[1];
  const float* bx = (const float*)d_in[2];
  const float* Wl = (const float*)d_in[3];
  const float* Wr = (const float*)d_in[4];
  const float* emb_table = (const float*)d_in[5];
  float* out = (float*)d_out;

  // Workspace layout (~25 MB)
  float* ws = (float*)d_ws;
  float* cA = ws;                               // 8192*256 f32
  float* cB = cA + 8192 * 256;                  // 4096*256 f32
  float* bias5 = cB + 4096 * 256;               // 1280 f32
  unsigned short* hA = (unsigned short*)(bias5 + 1280);  // 8192*256 bf16
  unsigned short* hB = hA + 8192 * 256;                  // 4096*256 bf16
  unsigned short* Wcf = hB + 4096 * 256;                 // 1280*512
  unsigned short* Wxf = Wcf + 1280 * 512;                // 480*512
  unsigned short* eb = Wxf + 480 * 512;                  // 8192*320

  // Vectorized prep (1725 blocks)
  k_prep<<<NB_EB + NB_WCF + NB_WXF + 5, 256, 0, stream>>>(
      embs, Wx, bx, Wl, Wr, emb_table + (in_sizes[5] - 300),
      eb, Wcf, Wxf, bias5);

  // Leaf -> cA (f32), hA (bf16); RT=2, row-affine slices
  k_leaf_mfma<<<1024, 256, 0, stream>>>(eb, Wxf, bx, cA, hA);

  // 13 tree levels
  const float* cs = cA;
  const unsigned short* hs = hA;
  int B = 4096;
  int lvl = 0;
  while (B >= 1) {
    float* dc;
    unsigned short* dh;
    float* dhf = nullptr;
    if (B == 1) {
      dc = out;
      dh = hB;  // dummy bf16 sink
      dhf = out + 256;
    } else if ((lvl & 1) == 0) {
      dc = cB; dh = hB;
    } else {
      dc = cA; dh = hA;
    }
    if (B == 4096) {
      int gx = (B >> 4) / 8;  // 32
      k_compose_mfma<2><<<gx * 16, 256, 0, stream>>>(
          hs, cs, Wcf, bias5, dc, dh, dhf, B);
    } else if (B >= 64) {
      int gx = (B >> 4) / 4;
      k_compose_mfma<1><<<gx * 16, 256, 0, stream>>>(
          hs, cs, Wcf, bias5, dc, dh, dhf, B);
    } else {
      k_compose_ksplit<<<dim3(1, 16), 256, 0, stream>>>(
          hs, cs, Wcf, bias5, dc, dh, dhf, B);
    }
    cs = dc;
    hs = dh;
    B >>= 1;
    lvl++;
  }
}

// Round 6
// 227.644 us; speedup vs baseline: 1.2746x; 1.0952x over previous
//
#include <hip/hip_runtime.h>
#include <math.h>

// BinaryTreeLSTM on MI355X — R9.
// vs R8 (249us):
//  (1) Generalized K-split compose for ALL levels B<=2048: block =
//      (tile-pair, grp); 4 waves x 4 kc + LDS reduce. 4x waves per level,
//      serial K-chain 16->4 kc, A-frags prefetched to regs up-front.
//      __launch_bounds__(256,4): <=128 VGPR, 4 blocks/CU x 40KB LDS = 160KB.
//  (2) Wcf/bias5 prep folded into the LEAF dispatch (they feed composes,
//      not leaf) -> one fewer launch, shuffle overlaps leaf MFMA.
//  (3) B=4096 keeps R8's RT=2 row-affine compose.
// Dispatches: prep1(eb,Wxf), leaf+Wcf+bias5, composeRT2(4096), ksplit x12 = 15.

#define MEM 256

typedef __attribute__((ext_vector_type(8))) short bf16x8;
typedef __attribute__((ext_vector_type(4))) float f32x4;

__device__ __forceinline__ float sigf(float x) { return 1.0f / (1.0f + __expf(-x)); }

__device__ __forceinline__ unsigned short f2b(float f) {
  unsigned int u = __float_as_uint(f);
  u = (u + 0x7FFFu + ((u >> 16) & 1u)) >> 16;
  return (unsigned short)u;
}

// 8 consecutive f32 -> bf16x8
__device__ __forceinline__ bf16x8 c8(const float* __restrict__ p) {
  float4 f0 = *(const float4*)(p);
  float4 f1 = *(const float4*)(p + 4);
  bf16x8 r;
  r[0] = (short)f2b(f0.x); r[1] = (short)f2b(f0.y);
  r[2] = (short)f2b(f0.z); r[3] = (short)f2b(f0.w);
  r[4] = (short)f2b(f1.x); r[5] = (short)f2b(f1.y);
  r[6] = (short)f2b(f1.z); r[7] = (short)f2b(f1.w);
  return r;
}

// 8 consecutive k from a 300-long f32 row, zero-padded past 300
__device__ __forceinline__ bf16x8 g8(const float* __restrict__ rp, int k0) {
  if (k0 + 8 <= 300) return c8(rp + k0);
  bf16x8 r;
#pragma unroll
  for (int j = 0; j < 8; j++) {
    int k = k0 + j;
    r[j] = (k < 300) ? (short)f2b(rp[k]) : (short)0;
  }
  return r;
}

// ---- Prep1: eb (embs->bf16) | Wxf shuffle ----
#define NB_EB 1280   // 8192*320/2048
#define NB_WXF 120   // 480*512/2048
__global__ __launch_bounds__(256) void k_prep1(
    const float* __restrict__ embs, const float* __restrict__ Wx,
    unsigned short* __restrict__ eb, unsigned short* __restrict__ Wxf) {
  int b = blockIdx.x, tid = threadIdx.x;
  if (b < NB_EB) {
    int idx8 = (b * 256 + tid) * 8;       // 8192*320
    int row = idx8 / 320;
    int k0 = idx8 - row * 320;
    *(bf16x8*)(eb + idx8) = g8(embs + row * 300, k0);
  } else {
    int idx8 = ((b - NB_EB) * 256 + tid) * 8;  // 480*512
    int f = idx8 >> 9, rr = idx8 & 511;
    int lane = rr >> 3;
    int gate = f % 3, t = f / 3;
    int grp = t & 15, kc = t >> 4;
    int k0 = kc * 32 + ((lane >> 4) << 3);
    const int gmap[3] = {0, 1, 3};
    int n = gmap[gate] * 256 + (grp << 4) + (lane & 15);
    *(bf16x8*)(Wxf + idx8) = g8(Wx + n * 300, k0);
  }
}

// ---- Leaf (0..1023) | Wcf shuffle (1024..1343) | bias5 (1344..1348) ----
#define NB_LEAF 1024
#define NB_WCF 320   // 1280*512/2048
__global__ __launch_bounds__(256) void k_leaf_fused(
    const unsigned short* __restrict__ eb, const unsigned short* __restrict__ Wxf,
    const float* __restrict__ bx, const float* __restrict__ Wx,
    const float* __restrict__ Wl, const float* __restrict__ Wr,
    const float* __restrict__ emb_last,
    unsigned short* __restrict__ Wcf, float* __restrict__ bias5,
    float* __restrict__ cO, unsigned short* __restrict__ hO) {
  int b = blockIdx.x, tid = threadIdx.x;
  if (b < NB_LEAF) {
    // leaf: row-affine slices, wave = 2 row tiles
    int slice = b & 7, rest = b >> 3;
    int rowblock = slice * 8 + (rest & 7);
    int grp = rest >> 3;
    int lane = tid & 63, wave = tid >> 6;
    int tb = (rowblock * 4 + wave) * 2;
    int m = lane & 15, quad = lane >> 4;

    f32x4 acc[2][3];
#pragma unroll
    for (int rt = 0; rt < 2; rt++)
#pragma unroll
      for (int g = 0; g < 3; g++) acc[rt][g] = (f32x4){0.f, 0.f, 0.f, 0.f};

    const unsigned short* ar0 = eb + (tb * 16 + m) * 320 + quad * 8;
    const unsigned short* ar1 = eb + ((tb + 1) * 16 + m) * 320 + quad * 8;
#pragma unroll
    for (int kc = 0; kc < 10; kc++) {
      const unsigned short* bp = Wxf + ((kc * 16 + grp) * 3) * 512 + lane * 8;
      bf16x8 b0 = *(const bf16x8*)(bp);
      bf16x8 b1 = *(const bf16x8*)(bp + 512);
      bf16x8 b2 = *(const bf16x8*)(bp + 1024);
      bf16x8 a0 = *(const bf16x8*)(ar0 + kc * 32);
      bf16x8 a1 = *(const bf16x8*)(ar1 + kc * 32);
      acc[0][0] = __builtin_amdgcn_mfma_f32_16x16x32_bf16(a0, b0, acc[0][0], 0, 0, 0);
      acc[0][1] = __builtin_amdgcn_mfma_f32_16x16x32_bf16(a0, b1, acc[0][1], 0, 0, 0);
      acc[0][2] = __builtin_amdgcn_mfma_f32_16x16x32_bf16(a0, b2, acc[0][2], 0, 0, 0);
      acc[1][0] = __builtin_amdgcn_mfma_f32_16x16x32_bf16(a1, b0, acc[1][0], 0, 0, 0);
      acc[1][1] = __builtin_amdgcn_mfma_f32_16x16x32_bf16(a1, b1, acc[1][1], 0, 0, 0);
      acc[1][2] = __builtin_amdgcn_mfma_f32_16x16x32_bf16(a1, b2, acc[1][2], 0, 0, 0);
    }
    int col = grp * 16 + m;
    float b0 = bx[col], b1 = bx[256 + col], b3 = bx[768 + col];
#pragma unroll
    for (int rt = 0; rt < 2; rt++) {
#pragma unroll
      for (int reg = 0; reg < 4; reg++) {
        int row = (tb + rt) * 16 + quad * 4 + reg;
        float u = tanhf(acc[rt][0][reg] + b0);
        float ig = sigf(acc[rt][1][reg] + b1);
        float o = sigf(acc[rt][2][reg] + b3);
        float c = ig * u;
        cO[row * MEM + col] = c;
        hO[row * MEM + col] = f2b(o * tanhf(c));
      }
    }
  } else if (b < NB_LEAF + NB_WCF) {
    int idx8 = ((b - NB_LEAF) * 256 + tid) * 8;  // 1280*512
    int f = idx8 >> 9, rr = idx8 & 511;
    int lane = rr >> 3;
    int gate = f % 5, t = f / 5;
    int grp = t & 15, kc = t >> 4;
    int k0 = kc * 32 + ((lane >> 4) << 3);
    int n = gate * 256 + (grp << 4) + (lane & 15);
    const float* src = (k0 < 256) ? (Wl + n * 256 + k0) : (Wr + n * 256 + (k0 - 256));
    *(bf16x8*)(Wcf + idx8) = c8(src);
  } else {
    int g = b - (NB_LEAF + NB_WCF);  // 0..4
    __shared__ float er[300];
    for (int k = tid; k < 300; k += 256) er[k] = emb_last[k];
    __syncthreads();
    const int map[5] = {0, 1, 2, 2, 3};
    int wrow = map[g] * 256 + tid;
    const float* w = Wx + wrow * 300;
    float s = bx[wrow];
    for (int k = 0; k < 300; k++) s += er[k] * w[k];
    bias5[g * 256 + tid] = s;
  }
}

// ---- Compose RT=2 (B=4096 only): 1-D grid(512), row-affine slices ----
__global__ __launch_bounds__(256) void k_compose_rt2(
    const unsigned short* __restrict__ hprev, const float* __restrict__ cprev,
    const unsigned short* __restrict__ Wcf, const float* __restrict__ bias5,
    float* __restrict__ cO, unsigned short* __restrict__ hO, int B) {
  int bid = blockIdx.x;
  int slice = bid & 7;
  int rest = bid >> 3;              // 0..63
  int rowblock = slice * 4 + (rest & 3);
  int grp = rest >> 2;              // 0..15
  int lane = threadIdx.x & 63;
  int wave = threadIdx.x >> 6;
  int tb = (rowblock * 4 + wave) * 2;
  int m = lane & 15, quad = lane >> 4;

  f32x4 acc[2][5];
  const unsigned short* ar[2];
#pragma unroll
  for (int rt = 0; rt < 2; rt++) {
    int ra = (tb + rt) * 16 + m;
    ar[rt] = hprev + ra * 512 + quad * 8;
#pragma unroll
    for (int g = 0; g < 5; g++) acc[rt][g] = (f32x4){0.f, 0.f, 0.f, 0.f};
  }

#pragma unroll
  for (int kc = 0; kc < 16; kc++) {
    const unsigned short* bp = Wcf + ((kc * 16 + grp) * 5) * 512 + lane * 8;
    bf16x8 b0 = *(const bf16x8*)(bp);
    bf16x8 b1 = *(const bf16x8*)(bp + 512);
    bf16x8 b2 = *(const bf16x8*)(bp + 1024);
    bf16x8 b3 = *(const bf16x8*)(bp + 1536);
    bf16x8 b4 = *(const bf16x8*)(bp + 2048);
#pragma unroll
    for (int rt = 0; rt < 2; rt++) {
      bf16x8 a = *(const bf16x8*)(ar[rt] + kc * 32);
      acc[rt][0] = __builtin_amdgcn_mfma_f32_16x16x32_bf16(a, b0, acc[rt][0], 0, 0, 0);
      acc[rt][1] = __builtin_amdgcn_mfma_f32_16x16x32_bf16(a, b1, acc[rt][1], 0, 0, 0);
      acc[rt][2] = __builtin_amdgcn_mfma_f32_16x16x32_bf16(a, b2, acc[rt][2], 0, 0, 0);
      acc[rt][3] = __builtin_amdgcn_mfma_f32_16x16x32_bf16(a, b3, acc[rt][3], 0, 0, 0);
      acc[rt][4] = __builtin_amdgcn_mfma_f32_16x16x32_bf16(a, b4, acc[rt][4], 0, 0, 0);
    }
  }
  int col = grp * 16 + m;
  float b0 = bias5[col], b1 = bias5[256 + col], b2 = bias5[512 + col];
  float b3 = bias5[768 + col], b4 = bias5[1024 + col];
#pragma unroll
  for (int rt = 0; rt < 2; rt++) {
#pragma unroll
    for (int reg = 0; reg < 4; reg++) {
      int row = (tb + rt) * 16 + quad * 4 + reg;
      float u = tanhf(acc[rt][0][reg] + b0);
      float ig = sigf(acc[rt][1][reg] + b1);
      float lf = sigf(acc[rt][2][reg] + b2);
      float rf = sigf(acc[rt][3][reg] + b3);
      float o = sigf(acc[rt][4][reg] + b4);
      float lc = cprev[(2 * row) * MEM + col];
      float rc = cprev[(2 * row + 1) * MEM + col];
      float c = ig * u + lf * lc + rf * rc;
      cO[row * MEM + col] = c;
      hO[row * MEM + col] = f2b(o * tanhf(c));
    }
  }
}

// ---- K-split compose, all B<=2048: grid(ceil(tiles/2),16) ----
// Block = (tile-pair tp, grp); wave w covers kc in [4w,4w+4); LDS reduce.
__global__ __launch_bounds__(256, 4) void k_compose_ksplit(
    const unsigned short* __restrict__ hprev, const float* __restrict__ cprev,
    const unsigned short* __restrict__ Wcf, const float* __restrict__ bias5,
    float* __restrict__ cO, unsigned short* __restrict__ hO,
    float* __restrict__ hOf, int B) {
  __shared__ __align__(16) float lds[4 * 2 * 5 * 64 * 4];  // 40KB
  int tid = threadIdx.x;
  int lane = tid & 63, wave = tid >> 6;
  int grp = blockIdx.y;
  int tp = blockIdx.x;
  int m = lane & 15, quad = lane >> 4;
  int tiles = (B + 15) >> 4;
  const bf16x8 zz = {0, 0, 0, 0, 0, 0, 0, 0};

  f32x4 acc[2][5];
  bool act[2], ok[2];
  bf16x8 av[2][4];  // A prefetched: [tile][kcl]
#pragma unroll
  for (int t = 0; t < 2; t++) {
    int gt = 2 * tp + t;
    act[t] = (gt < tiles);
    int ra = gt * 16 + m;
    ok[t] = act[t] && (ra < B);
    const unsigned short* ar = hprev + ra * 512 + quad * 8;
#pragma unroll
    for (int kcl = 0; kcl < 4; kcl++)
      av[t][kcl] = ok[t] ? *(const bf16x8*)(ar + (wave * 4 + kcl) * 32) : zz;
#pragma unroll
    for (int q = 0; q < 5; q++) acc[t][q] = (f32x4){0.f, 0.f, 0.f, 0.f};
  }

#pragma unroll
  for (int kcl = 0; kcl < 4; kcl++) {
    int kc = wave * 4 + kcl;
    const unsigned short* bp = Wcf + ((kc * 16 + grp) * 5) * 512 + lane * 8;
    bf16x8 b0 = *(const bf16x8*)(bp);
    bf16x8 b1 = *(const bf16x8*)(bp + 512);
    bf16x8 b2 = *(const bf16x8*)(bp + 1024);
    bf16x8 b3 = *(const bf16x8*)(bp + 1536);
    bf16x8 b4 = *(const bf16x8*)(bp + 2048);
#pragma unroll
    for (int t = 0; t < 2; t++) {
      if (act[t]) {
        acc[t][0] = __builtin_amdgcn_mfma_f32_16x16x32_bf16(av[t][kcl], b0, acc[t][0], 0, 0, 0);
        acc[t][1] = __builtin_amdgcn_mfma_f32_16x16x32_bf16(av[t][kcl], b1, acc[t][1], 0, 0, 0);
        acc[t][2] = __builtin_amdgcn_mfma_f32_16x16x32_bf16(av[t][kcl], b2, acc[t][2], 0, 0, 0);
        acc[t][3] = __builtin_amdgcn_mfma_f32_16x16x32_bf16(av[t][kcl], b3, acc[t][3], 0, 0, 0);
        acc[t][4] = __builtin_amdgcn_mfma_f32_16x16x32_bf16(av[t][kcl], b4, acc[t][4], 0, 0, 0);
      }
    }
  }
#pragma unroll
  for (int t = 0; t < 2; t++)
    if (act[t])
#pragma unroll
      for (int q = 0; q < 5; q++)
        *(f32x4*)&lds[(((wave * 2 + t) * 5 + q) * 64 + lane) * 4] = acc[t][q];
  __syncthreads();

  if (wave < 2 && act[wave]) {
    int t = wave;
    int gt = 2 * tp + t;
    int col = grp * 16 + m;
    float b0 = bias5[col], b1 = bias5[256 + col], b2 = bias5[512 + col];
    float b3 = bias5[768 + col], b4 = bias5[1024 + col];
    f32x4 s[5];
#pragma unroll
    for (int q = 0; q < 5; q++) {
      s[q] = *(const f32x4*)&lds[(((0 * 2 + t) * 5 + q) * 64 + lane) * 4];
#pragma unroll
      for (int v = 1; v < 4; v++) {
        f32x4 p = *(const f32x4*)&lds[(((v * 2 + t) * 5 + q) * 64 + lane) * 4];
        s[q][0] += p[0]; s[q][1] += p[1]; s[q][2] += p[2]; s[q][3] += p[3];
      }
    }
#pragma unroll
    for (int reg = 0; reg < 4; reg++) {
      int row = gt * 16 + quad * 4 + reg;
      if (row >= B) continue;
      float u = tanhf(s[0][reg] + b0);
      float ig = sigf(s[1][reg] + b1);
      float lf = sigf(s[2][reg] + b2);
      float rf = sigf(s[3][reg] + b3);
      float o = sigf(s[4][reg] + b4);
      float lc = cprev[(2 * row) * MEM + col];
      float rc = cprev[(2 * row + 1) * MEM + col];
      float c = ig * u + lf * lc + rf * rc;
      float h = o * tanhf(c);
      cO[row * MEM + col] = c;
      hO[row * MEM + col] = f2b(h);
      if (hOf) hOf[row * MEM + col] = h;
    }
  }
}

extern "C" void kernel_launch(void* const* d_in, const int* in_sizes, int n_in,
                              void* d_out, int out_size, void* d_ws, size_t ws_size,
                              hipStream_t stream) {
  const float* embs = (const float*)d_in[0];
  const float* Wx = (const float*)d_in[1];
  const float* bx = (const float*)d_in[2];
  const float* Wl = (const float*)d_in[3];
  const float* Wr = (const float*)d_in[4];
  const float* emb_table = (const float*)d_in[5];
  float* out = (float*)d_out;

  // Workspace layout (~25 MB)
  float* ws = (float*)d_ws;
  float* cA = ws;                               // 8192*256 f32
  float* cB = cA + 8192 * 256;                  // 4096*256 f32
  float* bias5 = cB + 4096 * 256;               // 1280 f32
  unsigned short* hA = (unsigned short*)(bias5 + 1280);  // 8192*256 bf16
  unsigned short* hB = hA + 8192 * 256;                  // 4096*256 bf16
  unsigned short* Wcf = hB + 4096 * 256;                 // 1280*512
  unsigned short* Wxf = Wcf + 1280 * 512;                // 480*512
  unsigned short* eb = Wxf + 480 * 512;                  // 8192*320

  // Prep1: eb + Wxf (1400 blocks)
  k_prep1<<<NB_EB + NB_WXF, 256, 0, stream>>>(embs, Wx, eb, Wxf);

  // Leaf (+ Wcf shuffle + bias5 overlapped) -> cA (f32), hA (bf16)
  k_leaf_fused<<<NB_LEAF + NB_WCF + 5, 256, 0, stream>>>(
      eb, Wxf, bx, Wx, Wl, Wr, emb_table + (in_sizes[5] - 300),
      Wcf, bias5, cA, hA);

  // B=4096: RT=2 row-affine compose -> cB, hB
  k_compose_rt2<<<512, 256, 0, stream>>>(hA, cA, Wcf, bias5, cB, hB, 4096);

  // B=2048..1: generalized K-split compose
  const float* cs = cB;
  const unsigned short* hs = hB;
  int B = 2048;
  int lvl = 1;
  while (B >= 1) {
    float* dc;
    unsigned short* dh;
    float* dhf = nullptr;
    if (B == 1) {
      dc = out;
      dh = hA;  // dummy bf16 sink
      dhf = out + 256;
    } else if ((lvl & 1) == 0) {
      dc = cB; dh = hB;
    } else {
      dc = cA; dh = hA;
    }
    int tiles = (B + 15) / 16;
    int gx = (tiles + 1) / 2;
    k_compose_ksplit<<<dim3(gx, 16), 256, 0, stream>>>(
        hs, cs, Wcf, bias5, dc, dh, dhf, B);
    cs = dc;
    hs = dh;
    B >>= 1;
    lvl++;
  }
}